// Round 5
// baseline (3626.380 us; speedup 1.0000x reference)
//
#include <hip/hip_runtime.h>

#define BATCH 64
#define SEQ 8192
#define RDIM 80
#define RING 169              // max delay 168 + 1
#define NCHUNK (SEQ / 2)      // 2 steps per chunk, 1 barrier per chunk
#define SLOT_BYTES (RDIM * 4)           // 320
#define RING_BYTES (RING * RDIM * 4)    // 54080

typedef float v2f __attribute__((ext_vector_type(2)));

__device__ __forceinline__ float fast_tanh(float z) {
    // tanh(z) = 1 - 2/(exp(2z)+1); exact saturation, abs err ~1e-7
    float e = __expf(2.0f * z);
    return 1.0f - 2.0f / (e + 1.0f);
}

// v + (v from lane ^ pattern) via DPP quad_perm (pure VALU, no LDS/SGPR hazard)
// 0xB1 = quad_perm(1,0,3,2) -> xor 1 ; 0x4E = quad_perm(2,3,0,1) -> xor 2
template <int CTRL>
__device__ __forceinline__ float dpp_xor_add(float v) {
    int o = __builtin_amdgcn_mov_dpp(__float_as_int(v), CTRL, 0xF, 0xF, true);
    return v + __int_as_float(o);
}

// 64 blocks on 256 CUs -> 1 block/CU; 4 waves on 4 SIMDs, 1 wave/SIMD.
__global__ __attribute__((amdgpu_flat_work_group_size(256, 256),
                          amdgpu_waves_per_eu(1, 1)))
void reservoir_kernel(const float* __restrict__ x,
                      const float* __restrict__ W_in,
                      const float* __restrict__ W_fb,
                      const float* __restrict__ bias,
                      float* __restrict__ out) {
    // ring[slot][i]: accumulated far-tap contributions for step s = slot (mod 169)
    __shared__ __align__(16) float ring[RING * RDIM];    // 54080 B
    // h_hist[s&3][i]: h for step s; wave0 writes, taps + wave0-broadcast read
    __shared__ __align__(16) float h_hist[4 * RDIM];     // 1280 B

    const int b    = blockIdx.x;
    const int t    = threadIdx.x;
    const int wid  = t >> 6;   // 0 = recurrence, 1..3 = taps (one SIMD each)
    const int lane = t & 63;

    for (int i = t; i < RING * RDIM; i += 256) ring[i] = 0.0f;
    for (int i = t; i < 4 * RDIM; i += 256) h_hist[i] = 0.0f;

    const float* xb   = x + (size_t)b * SEQ;
    float*       outb = out + (size_t)b * (size_t)SEQ * RDIM;

    v2f wr2[80];   // per-lane weight slice as packed pairs (wave0 uses first 50)

    // ---- wave-0 layout: quad q owns rows 5q..5q+4; lane (q,sub) covers j in [20*sub, 20*sub+20)
    int q = 0, sub = 0, rowA = 0, rowB = 0;
    float hA = 0.f, hB = 0.f, winA = 0.f, winB = 0.f, bA = 0.f, bB = 0.f;
    v2f hh2[10];   // wave0: broadcast h_{s-1} slice (packed), carried across steps
    int off0 = 0;  // wave0: byte offset of ring slot for step 2c (incremental, no %)
    // ---- tap layout (waves 1..3, both steps of the chunk):
    //      unit g = (wid-1)*64+lane < 160 ; k=g/40 -> tau{4,24,96,168};
    //      qq=(g%40)/2 -> rows 4qq..4qq+3 ; half=g&1 -> j in [40*half, 40*half+40)
    int qq = 0, half = 0;
    int offA = 0;  // taps: byte offset of ring[(sp0+tau) slot] + 16*qq (incremental)
    bool tap_valid = false, tap_lo = false;
    float x0 = 0.f, x1 = 0.f;

    if (wid == 0) {
        q = lane >> 2; sub = lane & 3;
        rowA = 5 * q + sub;        // owned by this lane
        rowB = 5 * q + 4;          // owned by sub==0 lane
        #pragma unroll
        for (int r = 0; r < 5; ++r) {
            const float* src = W_fb + (size_t)(5 * q + r) * RDIM + 20 * sub;  // W_1 rows
            #pragma unroll
            for (int j4 = 0; j4 < 5; ++j4) {
                float4 v = ((const float4*)src)[j4];
                wr2[r * 10 + 2 * j4 + 0] = (v2f){v.x, v.y};
                wr2[r * 10 + 2 * j4 + 1] = (v2f){v.z, v.w};
            }
        }
        winA = W_in[rowA]; bA = bias[rowA];
        winB = W_in[rowB]; bB = bias[rowB];
        #pragma unroll
        for (int j2 = 0; j2 < 10; ++j2) hh2[j2] = (v2f){0.f, 0.f};   // h_{-1} = 0
        x0 = xb[0]; x1 = xb[1];
    } else {
        int g = (wid - 1) * 64 + lane;
        tap_valid = (g < 160);
        int gg = tap_valid ? g : 159;
        int k = gg / 40, rem = gg % 40;
        qq = rem >> 1; half = rem & 1;
        tap_lo = (half == 0);
        const int taus[4] = {4, 24, 96, 168};
        int tap_tau = taus[k];
        // first processed chunk is c=1 (sp0=0): slot = tau
        offA = tap_tau * SLOT_BYTES + 16 * qq;
        #pragma unroll
        for (int r = 0; r < 4; ++r) {
            const float* src = W_fb + (size_t)(k + 1) * RDIM * RDIM
                                    + (size_t)(4 * qq + r) * RDIM + 40 * half;
            #pragma unroll
            for (int j4 = 0; j4 < 10; ++j4) {
                float4 v = ((const float4*)src)[j4];
                wr2[r * 20 + 2 * j4 + 0] = (v2f){v.x, v.y};
                wr2[r * 20 + 2 * j4 + 1] = (v2f){v.z, v.w};
            }
        }
    }

    __syncthreads();   // full fence once; in-loop barriers are raw s_barrier

    for (int c = 0; c < NCHUNK; ++c) {
        if (wid == 0) {
            // ================= recurrence wave: steps 2c, 2c+1 =================
            const int s0 = 2 * c;
            int off1 = off0 + SLOT_BYTES; if (off1 >= RING_BYTES) off1 -= RING_BYTES;
            float* p0 = (float*)((char*)ring + off0);
            float* p1 = (float*)((char*)ring + off1);
            // ring slots for this chunk are final (taps this chunk write slots >= 2c+2)
            float rgA0 = p0[rowA];
            float rgA1 = p1[rowA];
            float rgB0 = 0.f, rgB1 = 0.f;
            if (sub == 0) { rgB0 = p0[rowB]; rgB1 = p1[rowB]; }
            // retire the consumed slots for reuse 169 steps later
            p0[rowA] = 0.f; p1[rowA] = 0.f;
            if (sub == 0) { p0[rowB] = 0.f; p1[rowB] = 0.f; }
            off0 += 2 * SLOT_BYTES; if (off0 >= RING_BYTES) off0 -= RING_BYTES;
            // prefetch next chunk's x (8B aligned: s0+2 even)
            float xn0 = x0, xn1 = x1;
            if (s0 + 2 < SEQ) { float2 xn = *(const float2*)(xb + s0 + 2); xn0 = xn.x; xn1 = xn.y; }

            #pragma unroll
            for (int st = 0; st < 2; ++st) {
                const int s     = s0 + st;
                const float xs  = st ? x1   : x0;
                const float rgA = st ? rgA1 : rgA0;
                const float rgB = st ? rgB1 : rgB0;
                // hh2 already holds the broadcast h_{s-1} slice (prefetched last step)
                v2f dd2[5];
                #pragma unroll
                for (int r = 0; r < 5; ++r) dd2[r] = (v2f){0.f, 0.f};
                #pragma unroll
                for (int r = 0; r < 5; ++r)
                    #pragma unroll
                    for (int j2 = 0; j2 < 10; ++j2)
                        dd2[r] = __builtin_elementwise_fma(wr2[r * 10 + j2], hh2[j2], dd2[r]);
                float dd[5];
                #pragma unroll
                for (int r = 0; r < 5; ++r) dd[r] = dd2[r].x + dd2[r].y;
                // quad all-reduce: every lane gets full dots for its quad's 5 rows
                #pragma unroll
                for (int r = 0; r < 5; ++r) {
                    dd[r] = dpp_xor_add<0xB1>(dd[r]);
                    dd[r] = dpp_xor_add<0x4E>(dd[r]);
                }
                float dA = (sub == 0) ? dd[0] : (sub == 1) ? dd[1] : (sub == 2) ? dd[2] : dd[3];
                float zA = dA + rgA + bA + xs * winA;
                hA = 0.7f * hA + 0.3f * fast_tanh(zA);
                if (sub == 0) {
                    float zB = dd[4] + rgB + bB + xs * winB;
                    hB = 0.7f * hB + 0.3f * fast_tanh(zB);
                }
                // publish h_s to LDS history (taps read it next chunk)
                h_hist[(s & 3) * RDIM + rowA] = hA;
                if (sub == 0) h_hist[(s & 3) * RDIM + rowB] = hB;
                // immediately prefetch the broadcast slice for step s+1
                // (same-wave DS ordering: reads see the writes above; only wave0 writes h_hist)
                {
                    const float4* hp = (const float4*)(h_hist + (s & 3) * RDIM + 20 * sub);
                    #pragma unroll
                    for (int j4 = 0; j4 < 5; ++j4) {
                        float4 v = hp[j4];
                        hh2[2 * j4 + 0] = (v2f){v.x, v.y};
                        hh2[2 * j4 + 1] = (v2f){v.z, v.w};
                    }
                }
                // fire-and-forget output stores (never read by anyone; no vmcnt drain)
                outb[(size_t)s * RDIM + rowA] = hA;
                if (sub == 0) outb[(size_t)s * RDIM + rowB] = hB;
            }
            x0 = xn0; x1 = xn1;
        } else if (c > 0) {
            // ===== tap waves: steps 2(c-1), 2(c-1)+1 — ALL LDS loads hoisted =====
            const int sp0 = 2 * (c - 1);
            const float4* hp0 = (const float4*)(h_hist + (sp0 & 3) * RDIM + 40 * half);
            const float4* hp1 = (const float4*)(h_hist + ((sp0 + 1) & 3) * RDIM + 40 * half);
            // issue both steps' h loads (20 ds_read_b128) up front;
            // step-0 compute hides step-1's load latency
            v2f ha0[20], ha1[20];
            #pragma unroll
            for (int j4 = 0; j4 < 10; ++j4) {
                float4 v = hp0[j4];
                ha0[2 * j4 + 0] = (v2f){v.x, v.y}; ha0[2 * j4 + 1] = (v2f){v.z, v.w};
            }
            #pragma unroll
            for (int j4 = 0; j4 < 10; ++j4) {
                float4 v = hp1[j4];
                ha1[2 * j4 + 0] = (v2f){v.x, v.y}; ha1[2 * j4 + 1] = (v2f){v.z, v.w};
            }
            // hoist ring RMW reads too: slots sp0+{4,5,24,25,96,97,168,0}(mod 169)
            // are written by no other wave this chunk (wave0 zeroes only 2c,2c+1).
            // Unconditional load: (even,odd) lane pair shares the address -> free broadcast.
            int offB = offA + SLOT_BYTES; if (offB >= RING_BYTES) offB -= RING_BYTES;
            float4* pr0 = (float4*)((char*)ring + offA);
            float4* pr1 = (float4*)((char*)ring + offB);
            float4 rv0 = *pr0;
            float4 rv1 = *pr1;
            offA += 2 * SLOT_BYTES; if (offA >= RING_BYTES) offA -= RING_BYTES;

            v2f d0a[4], d1a[4];
            #pragma unroll
            for (int r = 0; r < 4; ++r) { d0a[r] = (v2f){0.f, 0.f}; d1a[r] = (v2f){0.f, 0.f}; }
            #pragma unroll
            for (int r = 0; r < 4; ++r)
                #pragma unroll
                for (int j2 = 0; j2 < 20; ++j2)
                    d0a[r] = __builtin_elementwise_fma(wr2[r * 20 + j2], ha0[j2], d0a[r]);
            #pragma unroll
            for (int r = 0; r < 4; ++r)
                #pragma unroll
                for (int j2 = 0; j2 < 20; ++j2)
                    d1a[r] = __builtin_elementwise_fma(wr2[r * 20 + j2], ha1[j2], d1a[r]);
            float d0[4], d1[4];
            #pragma unroll
            for (int r = 0; r < 4; ++r) { d0[r] = d0a[r].x + d0a[r].y; d1[r] = d1a[r].x + d1a[r].y; }
            // combine j-halves across the (even,odd) lane pair
            #pragma unroll
            for (int r = 0; r < 4; ++r) {
                d0[r] = dpp_xor_add<0xB1>(d0[r]);
                d1[r] = dpp_xor_add<0xB1>(d1[r]);
            }
            if (tap_valid && tap_lo) {
                rv0.x += d0[0]; rv0.y += d0[1]; rv0.z += d0[2]; rv0.w += d0[3];
                *pr0 = rv0;
                rv1.x += d1[0]; rv1.y += d1[1]; rv1.z += d1[2]; rv1.w += d1[3];
                *pr1 = rv1;
            }
        }
        // LDS-only fence + raw barrier: do NOT drain vmcnt (global stores in flight)
        asm volatile("s_waitcnt lgkmcnt(0)" ::: "memory");
        __builtin_amdgcn_s_barrier();
    }
}

extern "C" void kernel_launch(void* const* d_in, const int* in_sizes, int n_in,
                              void* d_out, int out_size, void* d_ws, size_t ws_size,
                              hipStream_t stream) {
    const float* x    = (const float*)d_in[0];   // (64, 8192, 1)
    const float* W_in = (const float*)d_in[1];   // (80, 1)
    const float* W_fb = (const float*)d_in[2];   // (5, 80, 80)
    const float* bias = (const float*)d_in[3];   // (80,)
    float* out        = (float*)d_out;           // (64, 8192, 80)

    reservoir_kernel<<<BATCH, 256, 0, stream>>>(x, W_in, W_fb, bias, out);
}